// Round 2
// baseline (417.029 us; speedup 1.0000x reference)
//
#include <hip/hip_runtime.h>
#include <math.h>

#define BATCH 8
#define SEQ   2048
#define CDIM  768
#define HDIM  64
#define NBLK  (SEQ / 64)   // 32 s-blocks — reference's multiplicative mask makes
                           // the FUTURE region dominate; must scan ALL of them.

// position of element d (0..63) within a swizzled 64-double LDS row; grp = row>>2.
// Keeps double2 (d even) pairs contiguous; rotation by grp spreads bank-pairs so
// column reads across rows are <=2-way conflicted (free).
static __device__ __forceinline__ int swz_off(int dp, int grp) {
    return ((dp + grp) & 31) * 2;
}

// ---------------------------------------------------------------- projection
// 512 blocks x 256 threads; each block computes q,k (fp64) and v (fp32) for 32 rows.
__global__ __launch_bounds__(256) void qkv_proj_kernel(
    const float* __restrict__ x,
    const float* __restrict__ Wk,
    const float* __restrict__ Wq,
    const float* __restrict__ Wv,
    double* __restrict__ qd,
    double* __restrict__ kd,
    float*  __restrict__ vf)
{
    __shared__ float xs[32][68];     // +4 pad: broadcast reads conflict-free
    __shared__ float wqs[64 * 64];
    __shared__ float wks[64 * 64];
    __shared__ float wvs[64 * 64];

    const int tid = threadIdx.x;
    const int tx  = tid & 15;        // dim group: dims 4*tx .. 4*tx+3
    const int ty  = tid >> 4;        // row group: rows 2*ty .. 2*ty+1
    const size_t row0 = (size_t)blockIdx.x * 32;

    double qa[2][4] = {{0, 0, 0, 0}, {0, 0, 0, 0}};
    double ka[2][4] = {{0, 0, 0, 0}, {0, 0, 0, 0}};
    float  va[2][4] = {{0, 0, 0, 0}, {0, 0, 0, 0}};

    for (int cc = 0; cc < CDIM; cc += 64) {
        __syncthreads();
        // stage x chunk: 32 rows x 64 cols = 512 float4
        #pragma unroll
        for (int it = 0; it < 2; ++it) {
            const int t  = tid + it * 256;
            const int r  = t >> 4;
            const int c4 = t & 15;
            const float4 v4 = *reinterpret_cast<const float4*>(
                &x[(row0 + r) * CDIM + cc + c4 * 4]);
            *reinterpret_cast<float4*>(&xs[r][c4 * 4]) = v4;
        }
        // stage W chunks (rows cc..cc+63 are contiguous): 1024 float4 each
        {
            const float4* wqg = reinterpret_cast<const float4*>(&Wq[(size_t)cc * HDIM]);
            const float4* wkg = reinterpret_cast<const float4*>(&Wk[(size_t)cc * HDIM]);
            const float4* wvg = reinterpret_cast<const float4*>(&Wv[(size_t)cc * HDIM]);
            float4* wql = reinterpret_cast<float4*>(wqs);
            float4* wkl = reinterpret_cast<float4*>(wks);
            float4* wvl = reinterpret_cast<float4*>(wvs);
            #pragma unroll
            for (int it = 0; it < 4; ++it) {
                const int t = tid + it * 256;
                wql[t] = wqg[t];
                wkl[t] = wkg[t];
                wvl[t] = wvg[t];
            }
        }
        __syncthreads();
        #pragma unroll 4
        for (int c = 0; c < 64; ++c) {
            const float4 wq4 = *reinterpret_cast<const float4*>(&wqs[c * 64 + tx * 4]);
            const float4 wk4 = *reinterpret_cast<const float4*>(&wks[c * 64 + tx * 4]);
            const float4 wv4 = *reinterpret_cast<const float4*>(&wvs[c * 64 + tx * 4]);
            #pragma unroll
            for (int i = 0; i < 2; ++i) {
                const float  xv = xs[ty * 2 + i][c];
                const double xd = (double)xv;
                qa[i][0] += xd * (double)wq4.x;
                qa[i][1] += xd * (double)wq4.y;
                qa[i][2] += xd * (double)wq4.z;
                qa[i][3] += xd * (double)wq4.w;
                ka[i][0] += xd * (double)wk4.x;
                ka[i][1] += xd * (double)wk4.y;
                ka[i][2] += xd * (double)wk4.z;
                ka[i][3] += xd * (double)wk4.w;
                va[i][0] += xv * wv4.x;
                va[i][1] += xv * wv4.y;
                va[i][2] += xv * wv4.z;
                va[i][3] += xv * wv4.w;
            }
        }
    }
    #pragma unroll
    for (int i = 0; i < 2; ++i) {
        const size_t row = row0 + ty * 2 + i;
        *reinterpret_cast<double2*>(&qd[row * HDIM + tx * 4])     = make_double2(qa[i][0], qa[i][1]);
        *reinterpret_cast<double2*>(&qd[row * HDIM + tx * 4 + 2]) = make_double2(qa[i][2], qa[i][3]);
        *reinterpret_cast<double2*>(&kd[row * HDIM + tx * 4])     = make_double2(ka[i][0], ka[i][1]);
        *reinterpret_cast<double2*>(&kd[row * HDIM + tx * 4 + 2]) = make_double2(ka[i][2], ka[i][3]);
        *reinterpret_cast<float4*>(&vf[row * HDIM + tx * 4]) =
            make_float4(va[i][0], va[i][1], va[i][2], va[i][3]);
    }
}

// ---------------------------------------------------------------- attention
// grid (32, 8): block = (t-tile tb, batch b); 64 rows per block, 256 threads,
// per-thread 4x4 score tile. Online softmax over ALL 32 s-blocks (the
// multiplicative -1e14 mask makes masked/future entries carry huge POSITIVE
// logits when raw<0 — they dominate the softmax and must be included).
__global__ __launch_bounds__(256) void attn_kernel(
    const double* __restrict__ qd,
    const double* __restrict__ kd,
    const float*  __restrict__ vf,
    float* __restrict__ out)
{
    __shared__ double qs[64 * 64];   // swizzled [row][d]
    __shared__ double ks[64 * 64];   // swizzled [col][d]
    __shared__ float  vs[64 * 64];   // [s][d] linear
    __shared__ float  ps[64 * 68];   // [row][s] padded

    const int tid = threadIdx.x;
    const int tx  = tid & 15;        // col group: cols 4*tx .. 4*tx+3
    const int ty  = tid >> 4;        // row group: rows 4*ty .. 4*ty+3
    const int tb  = blockIdx.x;      // 0..31
    const int b   = blockIdx.y;      // 0..7
    const int r0  = tb * 64;

    // stage q tile (swizzled)
    {
        const double2* src = reinterpret_cast<const double2*>(
            qd + ((size_t)b * SEQ + r0) * HDIM);
        #pragma unroll
        for (int it = 0; it < 8; ++it) {
            const int t  = tid + it * 256;      // 0..2047 double2
            const int r  = t >> 5;
            const int dp = t & 31;
            const double2 v2 = src[t];
            *reinterpret_cast<double2*>(&qs[r * 64 + swz_off(dp, r >> 2)]) = v2;
        }
    }

    double m[4];
    float  l[4];
    float  oacc[4][4];
    #pragma unroll
    for (int i = 0; i < 4; ++i) {
        m[i] = -1.0e300;
        l[i] = 0.f;
        #pragma unroll
        for (int j = 0; j < 4; ++j) oacc[i][j] = 0.f;
    }

    for (int sb = 0; sb < NBLK; ++sb) {
        __syncthreads();   // previous PV / q-staging complete before overwrite
        const size_t kvbase = ((size_t)b * SEQ + sb * 64) * HDIM;
        {
            const double2* ksrc = reinterpret_cast<const double2*>(kd + kvbase);
            #pragma unroll
            for (int it = 0; it < 8; ++it) {
                const int t  = tid + it * 256;
                const int r  = t >> 5;
                const int dp = t & 31;
                const double2 v2 = ksrc[t];
                *reinterpret_cast<double2*>(&ks[r * 64 + swz_off(dp, r >> 2)]) = v2;
            }
            const float4* vsrc = reinterpret_cast<const float4*>(vf + kvbase);
            #pragma unroll
            for (int it = 0; it < 4; ++it) {
                const int t = tid + it * 256;
                reinterpret_cast<float4*>(vs)[t] = vsrc[t];
            }
        }
        __syncthreads();

        // ---- scores: s[i][j] = sum_d q[4ty+i][d] * k[4tx+j][d]  (fp64)
        double s[4][4];
        #pragma unroll
        for (int i = 0; i < 4; ++i)
            #pragma unroll
            for (int j = 0; j < 4; ++j) s[i][j] = 0.0;

        #pragma unroll 2
        for (int dp = 0; dp < 32; ++dp) {
            const int qo = swz_off(dp, ty);
            const int ko = swz_off(dp, tx);
            double2 qv[4], kv[4];
            #pragma unroll
            for (int i = 0; i < 4; ++i)
                qv[i] = *reinterpret_cast<const double2*>(&qs[(4 * ty + i) * 64 + qo]);
            #pragma unroll
            for (int j = 0; j < 4; ++j)
                kv[j] = *reinterpret_cast<const double2*>(&ks[(4 * tx + j) * 64 + ko]);
            #pragma unroll
            for (int i = 0; i < 4; ++i)
                #pragma unroll
                for (int j = 0; j < 4; ++j)
                    s[i][j] += qv[i].x * kv[j].x + qv[i].y * kv[j].y;
        }

        // ---- faithful multiplicative mask + online softmax (fp64 logit domain)
        #pragma unroll
        for (int i = 0; i < 4; ++i) {
            const int rg = r0 + 4 * ty + i;
            double lg[4];
            double tm = -1.0e300;
            #pragma unroll
            for (int j = 0; j < 4; ++j) {
                const int cg = sb * 64 + 4 * tx + j;
                const double raw = s[i][j];
                const double logit = (cg <= rg)
                    ? (raw * 1.0) * 0.125
                    : (raw * -99999999999999.0) * 0.125;
                lg[j] = logit;
                tm = fmax(tm, logit);
            }
            #pragma unroll
            for (int off = 8; off > 0; off >>= 1)
                tm = fmax(tm, __shfl_xor(tm, off, 16));
            const double mnew = fmax(m[i], tm);
            const double dm   = m[i] - mnew;
            const float  sf   = (dm < -80.0) ? 0.f : expf((float)dm);
            m[i] = mnew;
            l[i] *= sf;
            #pragma unroll
            for (int j = 0; j < 4; ++j) oacc[i][j] *= sf;
            float psum = 0.f;
            #pragma unroll
            for (int j = 0; j < 4; ++j) {
                const double dlt = lg[j] - mnew;
                const float  p   = (dlt < -80.0) ? 0.f : expf((float)dlt);
                ps[(4 * ty + i) * 68 + 4 * tx + j] = p;
                psum += p;
            }
            #pragma unroll
            for (int off = 8; off > 0; off >>= 1)
                psum += __shfl_xor(psum, off, 16);
            l[i] += psum;
        }
        __syncthreads();

        // ---- PV: oacc[i][j] += sum_s p[row][s] * v[s][dim]
        #pragma unroll 4
        for (int cs = 0; cs < 64; ++cs) {
            const float4 vv = *reinterpret_cast<const float4*>(&vs[cs * 64 + tx * 4]);
            #pragma unroll
            for (int i = 0; i < 4; ++i) {
                const float p = ps[(4 * ty + i) * 68 + cs];
                oacc[i][0] += p * vv.x;
                oacc[i][1] += p * vv.y;
                oacc[i][2] += p * vv.z;
                oacc[i][3] += p * vv.w;
            }
        }
    }

    #pragma unroll
    for (int i = 0; i < 4; ++i) {
        const float inv = 1.0f / l[i];
        const size_t row = (size_t)b * SEQ + r0 + 4 * ty + i;
        *reinterpret_cast<float4*>(&out[row * HDIM + tx * 4]) =
            make_float4(oacc[i][0] * inv, oacc[i][1] * inv,
                        oacc[i][2] * inv, oacc[i][3] * inv);
    }
}

extern "C" void kernel_launch(void* const* d_in, const int* in_sizes, int n_in,
                              void* d_out, int out_size, void* d_ws, size_t ws_size,
                              hipStream_t stream)
{
    const float* x  = (const float*)d_in[0];
    const float* Wk = (const float*)d_in[1];
    const float* Wq = (const float*)d_in[2];
    const float* Wv = (const float*)d_in[3];
    float* out = (float*)d_out;

    // workspace layout: q (fp64) | k (fp64) | v (fp32)  — 20 MB total
    double* qd = (double*)d_ws;
    double* kd = qd + (size_t)BATCH * SEQ * HDIM;
    float*  vf = (float*)(kd + (size_t)BATCH * SEQ * HDIM);

    qkv_proj_kernel<<<dim3(512), dim3(256), 0, stream>>>(x, Wk, Wq, Wv, qd, kd, vf);
    attn_kernel<<<dim3(32, 8), dim3(256), 0, stream>>>(qd, kd, vf, out);
}